// Round 10
// baseline (1405.279 us; speedup 1.0000x reference)
//
#include <hip/hip_runtime.h>
#include <hip/hip_fp16.h>

typedef _Float16 half8 __attribute__((ext_vector_type(8)));
typedef _Float16 half4v __attribute__((ext_vector_type(4)));
typedef float f32x4 __attribute__((ext_vector_type(4)));

#define T_INS 200

// LDS layout (bytes)
constexpr int WI0O = 0;       // 128 KiB: W_ih[0] as MFMA A-fragments
constexpr int H0O  = 131072;  // 2 x 4096 (parity)
constexpr int H1O  = 139264;  // 2 x 4096
constexpr int XTO  = 147456;  // 2 x 4096
constexpr int BIO  = 155648;  // float[2][512] gate-interleaved biases (pre-scaled)
constexpr int SMSZ = 159744;  // 156 KiB

constexpr size_t WSZ_PACK = 524288;  // 4 x 128KB frag regions

// swizzled [batch][k(half)] f16 layout (2-way max bank aliasing on b128)
#define OFF(b, k) (((((b) << 8) | ((k) << 1))) ^ (((b) & 7) << 4))

#define BAR_K(n) asm volatile("s_waitcnt lgkmcnt(" #n ")\n\ts_barrier" ::: "memory")
#define SCHED_FENCE() __builtin_amdgcn_sched_barrier(0)

__device__ __forceinline__ float sigm(float x) {
  return __builtin_amdgcn_rcpf(1.0f + __builtin_amdgcn_exp2f(-1.44269504f * x));
}
__device__ __forceinline__ float tanh_f(float x) {
  return 1.0f - 2.0f * __builtin_amdgcn_rcpf(1.0f + __builtin_amdgcn_exp2f(2.88539008f * x));
}
__device__ __forceinline__ half8 cvt_frag(const float* __restrict__ src) {
  f32x4 a = *(const f32x4*)src;
  f32x4 b = *(const f32x4*)(src + 4);
  half8 h;
  h[0] = (_Float16)a[0]; h[1] = (_Float16)a[1]; h[2] = (_Float16)a[2]; h[3] = (_Float16)a[3];
  h[4] = (_Float16)b[0]; h[5] = (_Float16)b[1]; h[6] = (_Float16)b[2]; h[7] = (_Float16)b[3];
  return h;
}
__device__ __forceinline__ half8 cvt_frag_s(const float* __restrict__ src, float s) {
  f32x4 a = *(const f32x4*)src;
  f32x4 b = *(const f32x4*)(src + 4);
  half8 h;
  h[0] = (_Float16)(s * a[0]); h[1] = (_Float16)(s * a[1]);
  h[2] = (_Float16)(s * a[2]); h[3] = (_Float16)(s * a[3]);
  h[4] = (_Float16)(s * b[0]); h[5] = (_Float16)(s * b[1]);
  h[6] = (_Float16)(s * b[2]); h[7] = (_Float16)(s * b[3]);
  return h;
}
// 8-wave row permutation: gate = r&3, unit = w*16 + (r>>2)*4 + mt
__device__ __forceinline__ int perm_row8(int w, int mt, int r) {
  return (r & 3) * 128 + w * 16 + (r >> 2) * 4 + mt;
}

// gates with pre-scaled z (SCALED: i,f,o rows x -log2e; g rows x 2*log2e)
template <int SCALED>
__device__ __forceinline__ float gates(const f32x4 a, float& c, bool mk) {
  float si, sf, tg, so;
  if (SCALED) {
    si = __builtin_amdgcn_rcpf(1.0f + __builtin_amdgcn_exp2f(a[0]));
    sf = __builtin_amdgcn_rcpf(1.0f + __builtin_amdgcn_exp2f(a[1]));
    tg = 1.0f - 2.0f * __builtin_amdgcn_rcpf(1.0f + __builtin_amdgcn_exp2f(a[2]));
    so = __builtin_amdgcn_rcpf(1.0f + __builtin_amdgcn_exp2f(a[3]));
  } else {
    si = sigm(a[0]); sf = sigm(a[1]); tg = tanh_f(a[2]); so = sigm(a[3]);
  }
  float cn = sf * c + si * tg;
  float hn = so * tanh_f(cn);
  c = mk ? cn : c;
  return hn;
}

// Pack into ws (PRE-SCALED rows): region 0 = W_ih[1], 1 = W_hh[0],
// 2 = W_hh[1], 3 = W_ih[0]. Frag F = w*16 + mt*4 + kf; 64 lanes x 16B.
__global__ __launch_bounds__(256) void pack_kernel(const float* __restrict__ W_ih,
                                                   const float* __restrict__ W_hh,
                                                   char* __restrict__ ws) {
  int gid = blockIdx.x * 256 + threadIdx.x;  // 32768 threads exactly
  int G = gid >> 6, lane = gid & 63;
  int region = G >> 7, F = G & 127;
  int w = F >> 4, mt = (F >> 2) & 3, kf = F & 3;
  int r = lane & 15;
  int row = perm_row8(w, mt, r);
  int k0 = kf * 32 + (lane >> 4) * 8;
  float s = ((r & 3) == 2) ? 2.88539008f : -1.44269504f;
  const float* src;
  if (region == 0)      src = W_ih + (size_t)(512 + row) * 128 + k0;
  else if (region == 3) src = W_ih + (size_t)row * 128 + k0;
  else                  src = W_hh + (size_t)((region - 1) * 512 + row) * 128 + k0;
  *(half8*)(ws + (size_t)G * 1024 + lane * 16) = cvt_frag_s(src, s);
}

#define READ_BF(BF, BASE)                                                     \
  _Pragma("unroll") for (int kf = 0; kf < 4; ++kf)                            \
      BF[kf] = *(const half8*)((BASE) + OFF(lb, kf * 32 + k0b));

#define MFMA4x4(ACC, WREG, BF)                                                \
  _Pragma("unroll") for (int kf = 0; kf < 4; ++kf)                            \
      _Pragma("unroll") for (int mt = 0; mt < 4; ++mt)                        \
          ACC[mt] = __builtin_amdgcn_mfma_f32_16x16x32_f16(WREG[mt][kf],      \
                                                           BF[kf], ACC[mt], 0, 0, 0);

#define MFMA_WI0(ACC, BF)                                                     \
  _Pragma("unroll") for (int kf = 0; kf < 4; ++kf)                            \
      _Pragma("unroll") for (int mt = 0; mt < 4; ++mt) {                      \
        half8 a_ = *(const half8*)(wi0base + (mt * 4 + kf) * 1024);           \
        ACC[mt] = __builtin_amdgcn_mfma_f32_16x16x32_f16(a_, BF[kf], ACC[mt], 0, 0, 0); \
      }

template <int PACKED>
__global__ __launch_bounds__(512, 2) void lstm_kernel(
    const float* __restrict__ x, const int* __restrict__ len_in,
    const int* __restrict__ len_ar, const float* __restrict__ W_ih,
    const float* __restrict__ W_hh, const float* __restrict__ b_ih,
    const float* __restrict__ b_hh, const char* __restrict__ ws,
    float* __restrict__ out) {
  __shared__ __attribute__((aligned(16))) char sm[SMSZ];
  float* biasS = (float*)(sm + BIO);

  const int tid = threadIdx.x;
  const int w = tid >> 6, lane = tid & 63;
  const int lb = lane & 15, lg = lane >> 4;
  const int k0b = lg * 8;
  const int u0 = w * 16 + lg * 4;
  const int batch = blockIdx.x * 16 + lb;
  const int Lin = len_in[batch];
  const int Lar = len_ar[batch];

  // ---- one-time init ----
  if (PACKED) {
    // W_ih[0] frags (pre-scaled) copied from ws region 3 into LDS
    for (int j = 0; j < 16; ++j) {
      int pos = j * 8192 + tid * 16;
      *(half8*)(sm + WI0O + pos) = *(const half8*)(ws + 393216 + pos);
    }
  } else {
    for (int j = 0; j < 16; ++j) {
      int pos = tid * 256 + j * 16;
      int F = pos >> 10, ln = (pos >> 4) & 63;
      int fw = F >> 4, fmt = (F >> 2) & 3, fkf = F & 3;
      int row = perm_row8(fw, fmt, ln & 15);
      int k0 = fkf * 32 + (ln >> 4) * 8;
      *(half8*)(sm + WI0O + pos) = cvt_frag(W_ih + (size_t)row * 128 + k0);
    }
  }
  // gate-interleaved biases (pre-scaled when PACKED)
  for (int i = tid; i < 1024; i += 512) {
    int l = i >> 9, rp = i & 511, u = rp >> 2, q = rp & 3;
    float s = PACKED ? ((q == 2) ? 2.88539008f : -1.44269504f) : 1.0f;
    biasS[i] = s * (b_ih[l * 512 + q * 128 + u] + b_hh[l * 512 + q * 128 + u]);
  }
  // zero h0/h1 (both parities)
#pragma unroll
  for (int i = 0; i < 2; ++i)
    *(f32x4*)(sm + H0O + tid * 16 + i * 8192) = (f32x4){0.f, 0.f, 0.f, 0.f};
  // stage x(0)->XT[0], x(1)->XT[1]
  const int xb = tid >> 5, xk4 = (tid & 31) * 4;
  {
    const float* xp0 = x + ((size_t)(blockIdx.x * 16 + xb) * T_INS) * 128 + xk4;
    f32x4 v0 = *(const f32x4*)xp0;
    f32x4 v1 = *(const f32x4*)(xp0 + 128);
    half4v h0x, h1x;
#pragma unroll
    for (int i = 0; i < 4; ++i) { h0x[i] = (_Float16)v0[i]; h1x[i] = (_Float16)v1[i]; }
    *(half4v*)(sm + XTO + OFF(xb, xk4)) = h0x;
    *(half4v*)(sm + XTO + 4096 + OFF(xb, xk4)) = h1x;
  }

  // resident weights: 48 half8 = 192 regs/wave (AGPR+VGPR)
  half8 whh0[4][4], whh1[4][4], wi1[4][4];
  if (PACKED) {
    const char* base = ws + (size_t)lane * 16;
#pragma unroll
    for (int mt = 0; mt < 4; ++mt)
#pragma unroll
      for (int kf = 0; kf < 4; ++kf) {
        int fo = (w * 16 + mt * 4 + kf) * 1024;
        wi1[mt][kf]  = *(const half8*)(base + fo);
        whh0[mt][kf] = *(const half8*)(base + 131072 + fo);
        whh1[mt][kf] = *(const half8*)(base + 262144 + fo);
      }
  } else {
#pragma unroll
    for (int mt = 0; mt < 4; ++mt)
#pragma unroll
      for (int kf = 0; kf < 4; ++kf) {
        int row = perm_row8(w, mt, lb);
        wi1[mt][kf]  = cvt_frag(W_ih + (size_t)(512 + row) * 128 + kf * 32 + k0b);
        whh0[mt][kf] = cvt_frag(W_hh + (size_t)row * 128 + kf * 32 + k0b);
        whh1[mt][kf] = cvt_frag(W_hh + (size_t)(512 + row) * 128 + kf * 32 + k0b);
      }
  }

  float c0[4], c1[4];
  half4v hp0v, hp1v;
#pragma unroll
  for (int i = 0; i < 4; ++i) {
    c0[i] = c1[i] = 0.f;
    hp0v[i] = (_Float16)0.f; hp1v[i] = (_Float16)0.f;
  }
  __syncthreads();

  const char* wi0base = sm + WI0O + w * 16384 + lane * 16;
  const float* xptr = x + ((size_t)(blockIdx.x * 16 + xb) * T_INS + 2) * 128 + xk4;
  float* optr = out + (size_t)batch * 25600 + u0;
  const size_t obase_ar = 13107200ull + (size_t)batch * 25600 + u0;

  f32x4 acc0[4], acc1[4];
  half8 bfA[4], bfB[4];

  // ---- prologue: layer0(0) ----
  {
    READ_BF(bfB, sm + XTO);  // x(0)
#pragma unroll
    for (int mt = 0; mt < 4; ++mt) acc0[mt] = *(const f32x4*)(biasS + (u0 + mt) * 4);
    MFMA_WI0(acc0, bfB);
    const bool mk0 = (0 < Lin);
    half4v h4;
#pragma unroll
    for (int mt = 0; mt < 4; ++mt) h4[mt] = (_Float16)gates<PACKED>(acc0[mt], c0[mt], mk0);
    hp0v = mk0 ? h4 : hp0v;
    *(half4v*)(sm + H0O + OFF(lb, u0)) = hp0v;  // h0(0) -> parity 0
    SCHED_FENCE();
#pragma unroll
    for (int mt = 0; mt < 4; ++mt) acc1[mt] = *(const f32x4*)(biasS + 512 + (u0 + mt) * 4);
#pragma unroll
    for (int mt = 0; mt < 4; ++mt) acc0[mt] = *(const f32x4*)(biasS + (u0 + mt) * 4);
    SCHED_FENCE();
    BAR_K(8);
  }

  // ---- TF merged loop: iteration t computes layer1(t) + layer0(t+1),
  //      ONE barrier per iteration (parity analysis: all intra-iter writes
  //      target the opposite parity of same-buffer reads). ----
  for (int t = 0; t < 199; ++t) {
    const int p = t & 1;
    const bool doX = (t < 198);
    f32x4 xpre;
    if (doX) { xpre = *(const f32x4*)xptr; xptr += 128; }
    const bool mk1 = (t < Lin), mk0 = ((t + 1) < Lin);

    READ_BF(bfB, sm + H1O + (p ^ 1) * 4096);  // h1(t-1)
    READ_BF(bfA, sm + H0O + p * 4096);        // h0(t) (feeds wi1 AND whh0)
    MFMA4x4(acc1, whh1, bfB);
    MFMA4x4(acc0, whh0, bfA);
    MFMA4x4(acc1, wi1, bfA);
    READ_BF(bfB, sm + XTO + (p ^ 1) * 4096);  // x(t+1)
    MFMA_WI0(acc0, bfB);

    // ACT1(t) + output
    {
      half4v h4; f32x4 vo;
#pragma unroll
      for (int mt = 0; mt < 4; ++mt) {
        float hn = gates<PACKED>(acc1[mt], c1[mt], mk1);
        h4[mt] = (_Float16)hn;
        vo[mt] = mk1 ? hn : 0.0f;
      }
      hp1v = mk1 ? h4 : hp1v;
      *(half4v*)(sm + H1O + p * 4096 + OFF(lb, u0)) = hp1v;
      *(f32x4*)optr = vo; optr += 128;
    }
    // ACT0(t+1)
    {
      half4v h4;
#pragma unroll
      for (int mt = 0; mt < 4; ++mt) h4[mt] = (_Float16)gates<PACKED>(acc0[mt], c0[mt], mk0);
      hp0v = mk0 ? h4 : hp0v;
      *(half4v*)(sm + H0O + (p ^ 1) * 4096 + OFF(lb, u0)) = hp0v;
    }
    // stage x(t+2)
    if (doX) {
      half4v hx;
#pragma unroll
      for (int i = 0; i < 4; ++i) hx[i] = (_Float16)xpre[i];
      *(half4v*)(sm + XTO + p * 4096 + OFF(xb, xk4)) = hx;
    }
    SCHED_FENCE();
#pragma unroll
    for (int mt = 0; mt < 4; ++mt) acc1[mt] = *(const f32x4*)(biasS + 512 + (u0 + mt) * 4);
#pragma unroll
    for (int mt = 0; mt < 4; ++mt) acc0[mt] = *(const f32x4*)(biasS + (u0 + mt) * 4);
    SCHED_FENCE();
    BAR_K(8);
  }

  // ---- epilogue: layer1(199) ----
  {
    READ_BF(bfB, sm + H1O);          // h1(198) @ parity 0
    READ_BF(bfA, sm + H0O + 4096);   // h0(199) @ parity 1 (carries into AR)
    MFMA4x4(acc1, whh1, bfB);
    MFMA4x4(acc1, wi1, bfA);
    BAR_K(0);  // all waves' reads landed -> safe to overwrite H1O[0]
    const bool mk1 = (199 < Lin);
    half4v h4; f32x4 vo;
#pragma unroll
    for (int mt = 0; mt < 4; ++mt) {
      float hn = gates<PACKED>(acc1[mt], c1[mt], mk1);
      h4[mt] = (_Float16)hn;
      vo[mt] = mk1 ? hn : 0.0f;
    }
    hp1v = mk1 ? h4 : hp1v;
    *(half4v*)(sm + H1O + OFF(lb, u0)) = hp1v;  // h1(199) -> parity 0 (AR reads p=0)
    *(f32x4*)optr = vo;
    optr = out + obase_ar;
    SCHED_FENCE();
#pragma unroll
    for (int mt = 0; mt < 4; ++mt) acc0[mt] = *(const f32x4*)(biasS + (u0 + mt) * 4);
    SCHED_FENCE();
    BAR_K(4);
  }

  // ---- AR loop (R7 2-barrier structure; bfA carries h0(t-1)) ----
  for (int t = 200; t < 400; ++t) {
    const int p = t & 1;
    const bool mk = (t - 200) < Lar;
    // layer 0
    MFMA4x4(acc0, whh0, bfA);                 // H = h0(t-1) carried
    READ_BF(bfB, sm + H1O + p * 4096);        // h1(t-1) (X-operand; carries to hh1)
    MFMA_WI0(acc0, bfB);
    {
      half4v h4;
#pragma unroll
      for (int mt = 0; mt < 4; ++mt) h4[mt] = (_Float16)gates<PACKED>(acc0[mt], c0[mt], mk);
      hp0v = mk ? h4 : hp0v;
      *(half4v*)(sm + H0O + p * 4096 + OFF(lb, u0)) = hp0v;
    }
    SCHED_FENCE();
#pragma unroll
    for (int mt = 0; mt < 4; ++mt) acc1[mt] = *(const f32x4*)(biasS + 512 + (u0 + mt) * 4);
    SCHED_FENCE();
    BAR_K(4);
    // layer 1
    MFMA4x4(acc1, whh1, bfB);                 // H = h1(t-1)
    READ_BF(bfA, sm + H0O + p * 4096);        // fresh h0(t) (carries to next hh0)
    MFMA4x4(acc1, wi1, bfA);
    {
      half4v h4; f32x4 vo;
#pragma unroll
      for (int mt = 0; mt < 4; ++mt) {
        float hn = gates<PACKED>(acc1[mt], c1[mt], mk);
        h4[mt] = (_Float16)hn;
        vo[mt] = mk ? hn : 0.0f;
      }
      hp1v = mk ? h4 : hp1v;
      *(half4v*)(sm + H1O + (p ^ 1) * 4096 + OFF(lb, u0)) = hp1v;
      *(f32x4*)optr = vo; optr += 128;
    }
    SCHED_FENCE();
#pragma unroll
    for (int mt = 0; mt < 4; ++mt) acc0[mt] = *(const f32x4*)(biasS + (u0 + mt) * 4);
    SCHED_FENCE();
    BAR_K(4);
  }
}

extern "C" void kernel_launch(void* const* d_in, const int* in_sizes, int n_in,
                              void* d_out, int out_size, void* d_ws, size_t ws_size,
                              hipStream_t stream) {
  (void)in_sizes; (void)n_in; (void)out_size;
  const float* x = (const float*)d_in[0];
  const int* len_in = (const int*)d_in[1];
  const int* len_ar = (const int*)d_in[2];
  // d_in[3] = mask_aureg unused (monotone mask recomputed from lengths)
  const float* W_ih = (const float*)d_in[4];
  const float* W_hh = (const float*)d_in[5];
  const float* b_ih = (const float*)d_in[6];
  const float* b_hh = (const float*)d_in[7];
  float* out = (float*)d_out;
  char* ws = (char*)d_ws;

  if (ws_size >= WSZ_PACK) {
    pack_kernel<<<dim3(128), dim3(256), 0, stream>>>(W_ih, W_hh, ws);
    lstm_kernel<1><<<dim3(32), dim3(512), 0, stream>>>(x, len_in, len_ar, W_ih,
                                                       W_hh, b_ih, b_hh, ws, out);
  } else {
    lstm_kernel<0><<<dim3(32), dim3(512), 0, stream>>>(x, len_in, len_ar, W_ih,
                                                       W_hh, b_ih, b_hh, ws, out);
  }
}

// Round 11
// 1051.743 us; speedup vs baseline: 1.3361x; 1.3361x over previous
//
#include <hip/hip_runtime.h>
#include <hip/hip_fp16.h>

typedef _Float16 half8 __attribute__((ext_vector_type(8)));
typedef _Float16 half4v __attribute__((ext_vector_type(4)));
typedef float f32x4 __attribute__((ext_vector_type(4)));

#define T_INS 200

// LDS layout (bytes)
constexpr int WI0O = 0;       // 128 KiB: W_ih[0] as MFMA A-fragments
constexpr int H0O  = 131072;  // 2 x 4096 (parity)
constexpr int H1O  = 139264;  // 2 x 4096
constexpr int XTO  = 147456;  // 2 x 4096
constexpr int BIO  = 155648;  // float[2][512] gate-interleaved biases (pre-scaled)
constexpr int SMSZ = 159744;  // 156 KiB

constexpr size_t WSZ_PACK = 524288;  // 4 x 128KB frag regions

// swizzled [batch][k(half)] f16 layout (2-way max bank aliasing on b128)
#define OFF(b, k) (((((b) << 8) | ((k) << 1))) ^ (((b) & 7) << 4))

// counted barrier: publish LDS only; global loads/stores stay in flight
#define BARRIER() asm volatile("s_waitcnt lgkmcnt(0)\n\ts_barrier" ::: "memory")

__device__ __forceinline__ float sigm(float x) {
  return __builtin_amdgcn_rcpf(1.0f + __builtin_amdgcn_exp2f(-1.44269504f * x));
}
__device__ __forceinline__ float tanh_f(float x) {
  return 1.0f - 2.0f * __builtin_amdgcn_rcpf(1.0f + __builtin_amdgcn_exp2f(2.88539008f * x));
}
__device__ __forceinline__ half8 cvt_frag(const float* __restrict__ src) {
  f32x4 a = *(const f32x4*)src;
  f32x4 b = *(const f32x4*)(src + 4);
  half8 h;
  h[0] = (_Float16)a[0]; h[1] = (_Float16)a[1]; h[2] = (_Float16)a[2]; h[3] = (_Float16)a[3];
  h[4] = (_Float16)b[0]; h[5] = (_Float16)b[1]; h[6] = (_Float16)b[2]; h[7] = (_Float16)b[3];
  return h;
}
__device__ __forceinline__ half8 cvt_frag_s(const float* __restrict__ src, float s) {
  f32x4 a = *(const f32x4*)src;
  f32x4 b = *(const f32x4*)(src + 4);
  half8 h;
  h[0] = (_Float16)(s * a[0]); h[1] = (_Float16)(s * a[1]);
  h[2] = (_Float16)(s * a[2]); h[3] = (_Float16)(s * a[3]);
  h[4] = (_Float16)(s * b[0]); h[5] = (_Float16)(s * b[1]);
  h[6] = (_Float16)(s * b[2]); h[7] = (_Float16)(s * b[3]);
  return h;
}
// 8-wave row permutation: gate = r&3, unit = w*16 + (r>>2)*4 + mt
__device__ __forceinline__ int perm_row8(int w, int mt, int r) {
  return (r & 3) * 128 + w * 16 + (r >> 2) * 4 + mt;
}

// gates with pre-scaled z (SCALED: i,f,o rows x -log2e; g rows x 2*log2e)
template <int SCALED>
__device__ __forceinline__ float gates(const f32x4 a, float& c, bool mk) {
  float si, sf, tg, so;
  if (SCALED) {
    si = __builtin_amdgcn_rcpf(1.0f + __builtin_amdgcn_exp2f(a[0]));
    sf = __builtin_amdgcn_rcpf(1.0f + __builtin_amdgcn_exp2f(a[1]));
    tg = 1.0f - 2.0f * __builtin_amdgcn_rcpf(1.0f + __builtin_amdgcn_exp2f(a[2]));
    so = __builtin_amdgcn_rcpf(1.0f + __builtin_amdgcn_exp2f(a[3]));
  } else {
    si = sigm(a[0]); sf = sigm(a[1]); tg = tanh_f(a[2]); so = sigm(a[3]);
  }
  float cn = sf * c + si * tg;
  float hn = so * tanh_f(cn);
  c = mk ? cn : c;
  return hn;
}

// Pack into ws (PRE-SCALED rows): region 0 = W_ih[1], 1 = W_hh[0],
// 2 = W_hh[1], 3 = W_ih[0]. Frag F = w*16 + mt*4 + kf; 64 lanes x 16B.
__global__ __launch_bounds__(256) void pack_kernel(const float* __restrict__ W_ih,
                                                   const float* __restrict__ W_hh,
                                                   char* __restrict__ ws) {
  int gid = blockIdx.x * 256 + threadIdx.x;  // 32768 threads exactly
  int G = gid >> 6, lane = gid & 63;
  int region = G >> 7, F = G & 127;
  int w = F >> 4, mt = (F >> 2) & 3, kf = F & 3;
  int r = lane & 15;
  int row = perm_row8(w, mt, r);
  int k0 = kf * 32 + (lane >> 4) * 8;
  float s = ((r & 3) == 2) ? 2.88539008f : -1.44269504f;
  const float* src;
  if (region == 0)      src = W_ih + (size_t)(512 + row) * 128 + k0;
  else if (region == 3) src = W_ih + (size_t)row * 128 + k0;
  else                  src = W_hh + (size_t)((region - 1) * 512 + row) * 128 + k0;
  *(half8*)(ws + (size_t)G * 1024 + lane * 16) = cvt_frag_s(src, s);
}

template <int PACKED>
__global__ __launch_bounds__(512, 2) void lstm_kernel(
    const float* __restrict__ x, const int* __restrict__ len_in,
    const int* __restrict__ len_ar, const float* __restrict__ W_ih,
    const float* __restrict__ W_hh, const float* __restrict__ b_ih,
    const float* __restrict__ b_hh, const char* __restrict__ ws,
    float* __restrict__ out) {
  __shared__ __attribute__((aligned(16))) char sm[SMSZ];
  float* biasS = (float*)(sm + BIO);

  const int tid = threadIdx.x;
  const int w = tid >> 6, lane = tid & 63;
  const int lb = lane & 15, lg = lane >> 4;
  const int k0b = lg * 8;
  const int u0 = w * 16 + lg * 4;  // lane's 4 contiguous units: u0..u0+3
  const int batch = blockIdx.x * 16 + lb;
  const int Lin = len_in[batch];
  const int Lar = len_ar[batch];

  // ---- one-time init ----
  if (PACKED) {
    // W_ih[0] frags (pre-scaled) copied from ws region 3 into LDS
    for (int j = 0; j < 16; ++j) {
      int pos = j * 8192 + tid * 16;
      *(half8*)(sm + WI0O + pos) = *(const half8*)(ws + 393216 + pos);
    }
  } else {
    for (int j = 0; j < 16; ++j) {
      int pos = tid * 256 + j * 16;
      int F = pos >> 10, ln = (pos >> 4) & 63;
      int fw = F >> 4, fmt = (F >> 2) & 3, fkf = F & 3;
      int row = perm_row8(fw, fmt, ln & 15);
      int k0 = fkf * 32 + (ln >> 4) * 8;
      *(half8*)(sm + WI0O + pos) = cvt_frag(W_ih + (size_t)row * 128 + k0);
    }
  }
  // gate-interleaved biases: biasS[l*512 + u*4 + q] (pre-scaled when PACKED)
  for (int i = tid; i < 1024; i += 512) {
    int l = i >> 9, rp = i & 511, u = rp >> 2, q = rp & 3;
    float s = PACKED ? ((q == 2) ? 2.88539008f : -1.44269504f) : 1.0f;
    biasS[i] = s * (b_ih[l * 512 + q * 128 + u] + b_hh[l * 512 + q * 128 + u]);
  }
  // zero h0/h1 (both parities): 16 KiB, 512 threads x 16B x 2
#pragma unroll
  for (int i = 0; i < 2; ++i)
    *(f32x4*)(sm + H0O + tid * 16 + i * 8192) = (f32x4){0.f, 0.f, 0.f, 0.f};
  // x(t=0) -> XT[0]: 512 threads, each 4 floats
  const int xb = tid >> 5, xk4 = (tid & 31) * 4;
  {
    f32x4 v = *(const f32x4*)(x + ((size_t)(blockIdx.x * 16 + xb) * T_INS) * 128 + xk4);
    half4v hx;
    hx[0] = (_Float16)v[0]; hx[1] = (_Float16)v[1];
    hx[2] = (_Float16)v[2]; hx[3] = (_Float16)v[3];
    *(half4v*)(sm + XTO + OFF(xb, xk4)) = hx;
  }

  // resident weights: 48 half8 = 192 regs/wave (wave w's 4 mt-tiles)
  half8 whh0[4][4], whh1[4][4], wi1[4][4];
  if (PACKED) {
    const char* base = ws + (size_t)lane * 16;
#pragma unroll
    for (int mt = 0; mt < 4; ++mt)
#pragma unroll
      for (int kf = 0; kf < 4; ++kf) {
        int fo = (w * 16 + mt * 4 + kf) * 1024;
        wi1[mt][kf]  = *(const half8*)(base + fo);
        whh0[mt][kf] = *(const half8*)(base + 131072 + fo);
        whh1[mt][kf] = *(const half8*)(base + 262144 + fo);
      }
  } else {
#pragma unroll
    for (int mt = 0; mt < 4; ++mt)
#pragma unroll
      for (int kf = 0; kf < 4; ++kf) {
        int row = perm_row8(w, mt, lb);
        wi1[mt][kf]  = cvt_frag(W_ih + (size_t)(512 + row) * 128 + kf * 32 + k0b);
        whh0[mt][kf] = cvt_frag(W_hh + (size_t)row * 128 + kf * 32 + k0b);
        whh1[mt][kf] = cvt_frag(W_hh + (size_t)(512 + row) * 128 + kf * 32 + k0b);
      }
  }

  float c0[4], c1[4];
  half4v hp0v, hp1v;
#pragma unroll
  for (int i = 0; i < 4; ++i) {
    c0[i] = c1[i] = 0.f;
    hp0v[i] = (_Float16)0.f; hp1v[i] = (_Float16)0.f;
  }
  __syncthreads();

  // strength-reduced pointers
  const float* xptr = x + ((size_t)(blockIdx.x * 16 + xb) * T_INS + 1) * 128 + xk4;
  float* optr = out + (size_t)batch * 25600 + u0;
  const size_t obase_ar = 13107200ull + (size_t)batch * 25600 + u0;
  const char* wi0base = sm + WI0O + w * 16384 + lane * 16;

  for (int t = 0; t < 400; ++t) {
    const int p = t & 1;
    const bool doX = (t < 199);
    f32x4 xpre = (f32x4){0.f, 0.f, 0.f, 0.f};
    if (doX) { xpre = *(const f32x4*)xptr; xptr += 128; }
    const bool mk = (t < 200) ? (t < Lin) : ((t - 200) < Lar);

    // ================= layer 0 =================
    f32x4 acc[4];
    {
      const char* sX = (t < 200) ? (sm + XTO + p * 4096) : (sm + H1O + p * 4096);
      const char* sH = sm + H0O + (p ^ 1) * 4096;
      half8 bf[4];
      // acc starts at bias vector
#pragma unroll
      for (int mt = 0; mt < 4; ++mt)
        acc[mt] = *(const f32x4*)(biasS + (u0 + mt) * 4);
      // hh (resident) first
#pragma unroll
      for (int kf = 0; kf < 4; ++kf)
        bf[kf] = *(const half8*)(sH + OFF(lb, kf * 32 + k0b));
#pragma unroll
      for (int kf = 0; kf < 4; ++kf)
#pragma unroll
        for (int mt = 0; mt < 4; ++mt)
          acc[mt] = __builtin_amdgcn_mfma_f32_16x16x32_f16(whh0[mt][kf], bf[kf],
                                                           acc[mt], 0, 0, 0);
      // ih from LDS (reuse bf regs)
#pragma unroll
      for (int kf = 0; kf < 4; ++kf)
        bf[kf] = *(const half8*)(sX + OFF(lb, kf * 32 + k0b));
#pragma unroll
      for (int kf = 0; kf < 4; ++kf)
#pragma unroll
        for (int mt = 0; mt < 4; ++mt) {
          half8 a = *(const half8*)(wi0base + (mt * 4 + kf) * 1024);
          acc[mt] = __builtin_amdgcn_mfma_f32_16x16x32_f16(a, bf[kf], acc[mt], 0, 0, 0);
        }
    }
    // ACT0
    {
      _Float16 h4[4];
#pragma unroll
      for (int mt = 0; mt < 4; ++mt)
        h4[mt] = (_Float16)gates<PACKED>(acc[mt], c0[mt], mk);
      hp0v = mk ? *(half4v*)h4 : hp0v;
      *(half4v*)(sm + H0O + p * 4096 + OFF(lb, u0)) = hp0v;
    }
    BARRIER();  // h0[p] published; vmem stays in flight

    // stage x(t+1) into XT[p^1]
    if (doX) {
      half4v hx;
      hx[0] = (_Float16)xpre[0]; hx[1] = (_Float16)xpre[1];
      hx[2] = (_Float16)xpre[2]; hx[3] = (_Float16)xpre[3];
      *(half4v*)(sm + XTO + (p ^ 1) * 4096 + OFF(xb, xk4)) = hx;
    }

    // ================= layer 1 =================
    {
      const char* sX = sm + H0O + p * 4096;  // fresh h0(t)
      const char* sH = sm + H1O + p * 4096;  // h1(t-1)
      half8 bf[4];
#pragma unroll
      for (int mt = 0; mt < 4; ++mt)
        acc[mt] = *(const f32x4*)(biasS + 512 + (u0 + mt) * 4);
#pragma unroll
      for (int kf = 0; kf < 4; ++kf)
        bf[kf] = *(const half8*)(sH + OFF(lb, kf * 32 + k0b));
#pragma unroll
      for (int kf = 0; kf < 4; ++kf)
#pragma unroll
        for (int mt = 0; mt < 4; ++mt)
          acc[mt] = __builtin_amdgcn_mfma_f32_16x16x32_f16(whh1[mt][kf], bf[kf],
                                                           acc[mt], 0, 0, 0);
#pragma unroll
      for (int kf = 0; kf < 4; ++kf)
        bf[kf] = *(const half8*)(sX + OFF(lb, kf * 32 + k0b));
#pragma unroll
      for (int kf = 0; kf < 4; ++kf)
#pragma unroll
        for (int mt = 0; mt < 4; ++mt)
          acc[mt] = __builtin_amdgcn_mfma_f32_16x16x32_f16(wi1[mt][kf], bf[kf],
                                                           acc[mt], 0, 0, 0);
    }
    // ACT1 + output
    {
      _Float16 h4[4];
      f32x4 vo;
#pragma unroll
      for (int mt = 0; mt < 4; ++mt) {
        float hn = gates<PACKED>(acc[mt], c1[mt], mk);
        h4[mt] = (_Float16)hn;
        vo[mt] = mk ? hn : 0.0f;
      }
      hp1v = mk ? *(half4v*)h4 : hp1v;
      *(half4v*)(sm + H1O + (p ^ 1) * 4096 + OFF(lb, u0)) = hp1v;
      *(f32x4*)optr = vo;
      optr += 128;
      if (t == 199) optr = out + obase_ar;
    }
    BARRIER();  // h1[p^1], XT[p^1] published
  }
}

extern "C" void kernel_launch(void* const* d_in, const int* in_sizes, int n_in,
                              void* d_out, int out_size, void* d_ws, size_t ws_size,
                              hipStream_t stream) {
  (void)in_sizes; (void)n_in; (void)out_size;
  const float* x = (const float*)d_in[0];
  const int* len_in = (const int*)d_in[1];
  const int* len_ar = (const int*)d_in[2];
  // d_in[3] = mask_aureg unused (monotone mask recomputed from lengths)
  const float* W_ih = (const float*)d_in[4];
  const float* W_hh = (const float*)d_in[5];
  const float* b_ih = (const float*)d_in[6];
  const float* b_hh = (const float*)d_in[7];
  float* out = (float*)d_out;
  char* ws = (char*)d_ws;

  if (ws_size >= WSZ_PACK) {
    pack_kernel<<<dim3(128), dim3(256), 0, stream>>>(W_ih, W_hh, ws);
    lstm_kernel<1><<<dim3(32), dim3(512), 0, stream>>>(x, len_in, len_ar, W_ih,
                                                       W_hh, b_ih, b_hh, ws, out);
  } else {
    lstm_kernel<0><<<dim3(32), dim3(512), 0, stream>>>(x, len_in, len_ar, W_ih,
                                                       W_hh, b_ih, b_hh, ws, out);
  }
}